// Round 4
// baseline (2633.900 us; speedup 1.0000x reference)
//
#include <hip/hip_runtime.h>

// ---------------------------------------------------------------------------
// Factorized algorithm (verified rounds 2-11). Shells = ascending r2 rank:
//   r2 in {0,1,2,3,4,5,6,8,9,12} -> shell 0..9
// y[l][r][d][z] = sum_{taps t in shell r} sph_l[t] * x[d, xo+i, yo+j, z+kk]
// conv_r[s,e,z] = sum_{r,d} wfull[wig_w[s], r, e, d] * y[wig_b[s]][r][d][z]
// s=0:(w,b)=(0,0); s=1..9: w=1+(s-1)/3, b=1+(s-1)%3
// Round 13: Y2 permuted layout (stage-2 reads conflict-free), XT staging
//   decode with j in low bits (conflict-free b128 writes).
// Round 15: WT LDS-staging of W2 -> NEUTRAL (exonerated W-load latency).
//   Reverted here; W2 read from global (L2-resident, broadcast).
// Round 16: cross-phase software pipeline. Y2 double-buffered; each barrier
//   interval now runs S2(p-1) then S1(p) (S2 reads Y2[(p-1)&1], S1 writes
//   Y2[p&1] -- disjoint). The other interval is just the XT(p) write +
//   prefetch issue. Same barrier count, but all compute per phase sits in
//   ONE interval: one convergence per compute chunk instead of two, and two
//   independent FMA/LDS streams per wave for the scheduler to interleave.
//   LDS = Y2 2x15360 + XT 6400 + CT 3200 = 40320 B -> 4 blocks/CU.
//   NO __launch_bounds__ min-waves arg (r14: (192,4) => VGPR 64 => spills).
// ---------------------------------------------------------------------------

// prep: W2[p8][k20][e16][w4] (k=2r+di, d=2p+di) + CT2[l][25][8]
__global__ void prep_kernel(const float* __restrict__ weight,     // (4,9,16,16)
                            const float* __restrict__ zw,         // (16,16)
                            const float* __restrict__ bf,         // (4,10,125)
                            float* __restrict__ W2,               // 10240 f32
                            float* __restrict__ TAB)              // 800 f32
{
    int t = blockIdx.x * 256 + threadIdx.x;
    if (t < 10240) {
        int w = t & 3;
        int e = (t >> 2) & 15;
        int k = (t >> 6) % 20;
        int p = t / 1280;
        int r = k >> 1, di = k & 1, d = 2 * p + di;
        float v;
        if (r == 0) v = (w == 0) ? zw[e * 16 + d] : 0.f;
        else        v = weight[((w * 9 + (r - 1)) * 16 + e) * 16 + d];
        W2[t] = v;
    } else if (t < 10240 + 800) {
        int q = t - 10240;           // q = (l*25 + slice)*8 + kk
        int l = q / 200;
        int rem = q % 200;
        int slice = rem / 8, kk = rem % 8;
        float s = 0.f;
        if (kk < 5) {
            int tap = slice * 5 + kk;
            for (int r = 0; r < 10; ++r) s += bf[(l * 10 + r) * 125 + tap];
        }
        TAB[q] = s;                  // sph_l[tap] (masks partition the cube)
    }
}

__global__ __launch_bounds__(192) void fused_kernel(
    const float* __restrict__ x,    // (2,16,40,40,40)
    const float* __restrict__ W2,   // [p][k20][e16][w4]
    const float* __restrict__ TAB,  // CT2 [l][25][8]
    const float* __restrict__ g,    // (27,10)
    const float* __restrict__ w_i,  // (3,)
    const float* __restrict__ bias, // (16,)
    float* __restrict__ out)        // (2,16,36,36,36)
{
    __shared__ float Y2[2][3840];   // [buf][k20][perm(yo,z)][l4] permuted
    __shared__ float CT[800];       // [l4][25][8]
    __shared__ float XT[1600];      // [di2][i5][j8] rows of 20 (16 z used)

    const int tid = threadIdx.x;

    // XCD-chunked swizzle: 1944 blocks = 8 XCDs x 243 contiguous wgids
    const int bid  = blockIdx.x;
    const int wgid = (bid & 7) * 243 + (bid >> 3);
    const int xo  = wgid % 36;
    const int yoq = (wgid / 36) % 9;
    const int zs  = (wgid / 324) % 3;   // z base = 12*zs
    const int bb  = wgid / 972;

    // stage-1 decode (di2, l4, yo4, zt6): 2 z per thread
    const int s_zt = tid % 6;
    const int s_yo = (tid / 6) & 3;
    const int s_l  = (tid / 24) & 3;
    const int s_di = tid / 96;
    // stage-2 decode (e8, yo4, zt6): e = 2*c_e+{0,1}, z = 2*c_zt+{0,1}
    const int c_e  = tid & 7;
    const int c_yo = (tid >> 3) & 3;
    const int c_zt = tid / 32;

    for (int idx = tid; idx < 800; idx += 192) CT[idx] = TAB[idx];

    constexpr int RANKT[13] = {0, 1, 2, 3, 4, 5, 6, 0, 7, 8, 0, 0, 9};

    float acc[10][2][2];   // [s][e-sub][z] = 40 regs
    #pragma unroll
    for (int s = 0; s < 10; ++s)
        #pragma unroll
        for (int ee = 0; ee < 2; ++ee) { acc[s][ee][0] = 0.f; acc[s][ee][1] = 0.f; }

    const float* ct = CT + s_l * 200;

    // Y2 permuted bases:
    //   write (stage-1): z0 = 2*s_zt -> perm0 = (s_zt>>1)*8 + (s_zt&1)*4 + s_yo
    //                    word = k*192 + perm0*4 + s_l  (z1 = z0+1 at +96)
    //   read  (stage-2): same perm with (c_zt, c_yo); f4 over l at +0 / +96
    const int wbase = (((s_zt >> 1) * 8 + (s_zt & 1) * 4 + s_yo) << 2) + s_l;
    const int yb0   = (((c_zt >> 1) * 8 + (c_zt & 1) * 4 + c_yo) << 2);

    // ---- XT staging geometry: 320 float4 per phase, 2 slots per thread ----
    // decode: j in LOW bits -> conflict-free b128 LDS writes (group 5j+zq)
    const int idx0 = tid;
    const int idx1 = tid + 192;
    const bool has1 = idx1 < 320;
    const int j0 = idx0 & 7, zq0 = (idx0 >> 3) & 3, i0 = (idx0 >> 5) % 5, di0 = idx0 / 160;
    const int j1 = idx1 & 7, zq1 = (idx1 >> 3) & 3, i1 = (idx1 >> 5) % 5, di1 = idx1 / 160;
    const int xt0 = ((di0 * 5 + i0) * 8 + j0) * 20 + 4 * zq0;
    const int xt1 = ((di1 * 5 + i1) * 8 + j1) * 20 + 4 * zq1;
    const float* gsrc0 = x + ((((bb * 16 + di0) * 40 + xo + i0) * 40 + yoq * 4 + j0) * 40
                              + zs * 12 + 4 * zq0);
    const float* gsrc1 = x + ((((bb * 16 + di1) * 40 + xo + i1) * 40 + yoq * 4 + j1) * 40
                              + zs * 12 + 4 * zq1);

    // prologue: XT(0) direct; issue x loads for phase 1
    {
        float4 a = *(const float4*)gsrc0;
        float4 b = has1 ? *(const float4*)gsrc1 : make_float4(0.f, 0.f, 0.f, 0.f);
        *(float4*)(XT + xt0) = a;
        if (has1) *(float4*)(XT + xt1) = b;
    }
    gsrc0 += 128000;
    float4 pre0 = *(const float4*)gsrc0;
    float4 pre1 = make_float4(0.f, 0.f, 0.f, 0.f);
    if (has1) { gsrc1 += 128000; pre1 = *(const float4*)gsrc1; }

    // ================= stage-1 body (macro-free lambda) ====================
    auto stage1 = [&](float* __restrict__ Yw) {
        float yreg[10][2];
        #pragma unroll
        for (int r = 0; r < 10; ++r) { yreg[r][0] = 0.f; yreg[r][1] = 0.f; }

        const float* xt = XT + s_di * 800;
        #pragma unroll
        for (int i = 0; i < 5; ++i) {
            #pragma unroll
            for (int j = 0; j < 5; ++j) {
                const float* row = xt + (i * 8 + s_yo + j) * 20 + 2 * s_zt;
                const float2 a  = *(const float2*)(row);
                const float2 b2 = *(const float2*)(row + 2);
                const float2 d2 = *(const float2*)(row + 4);
                const float xv[6] = {a.x, a.y, b2.x, b2.y, d2.x, d2.y};
                const float* cs = ct + (i * 5 + j) * 8;
                const float4 c03 = *(const float4*)cs;   // one b128
                const float  c4v = cs[4];                // one b32
                #pragma unroll
                for (int kk = 0; kk < 5; ++kk) {
                    const int r2 = (i - 2) * (i - 2) + (j - 2) * (j - 2) + (kk - 2) * (kk - 2);
                    const int r  = RANKT[r2];            // compile-time
                    const float cc = (kk == 0) ? c03.x : (kk == 1) ? c03.y :
                                     (kk == 2) ? c03.z : (kk == 3) ? c03.w : c4v;
                    yreg[r][0] = fmaf(cc, xv[kk + 0], yreg[r][0]);
                    yreg[r][1] = fmaf(cc, xv[kk + 1], yreg[r][1]);
                }
            }
        }
        #pragma unroll
        for (int r = 0; r < 10; ++r) {
            // permuted Y2: word = k*192 + perm0*4 + l ; z1 at +96
            const int wb = (2 * r + s_di) * 192 + wbase;
            Yw[wb]      = yreg[r][0];    // fused into ds_write2_b32
            Yw[wb + 96] = yreg[r][1];
        }
    };

    // ================= stage-2 body ========================================
    auto stage2 = [&](const float* __restrict__ Yr, const float* __restrict__ W2p) {
        #pragma unroll
        for (int k = 0; k < 20; ++k) {
            const float4 wv0 = *(const float4*)(W2p + k * 64);
            const float4 wv1 = *(const float4*)(W2p + k * 64 + 4);
            const float* yb = Yr + k * 192 + yb0;
            const float4 yz0 = *(const float4*)(yb);       // l0..3 at z0
            const float4 yz1 = *(const float4*)(yb + 96);  // l0..3 at z1
            {   // b = 0 pairs only with w = 0 -> s = 0
                acc[0][0][0] = fmaf(wv0.x, yz0.x, acc[0][0][0]);
                acc[0][0][1] = fmaf(wv0.x, yz1.x, acc[0][0][1]);
                acc[0][1][0] = fmaf(wv1.x, yz0.x, acc[0][1][0]);
                acc[0][1][1] = fmaf(wv1.x, yz1.x, acc[0][1][1]);
            }
            #pragma unroll
            for (int b = 1; b < 4; ++b) {
                const float y0 = (b == 1) ? yz0.y : (b == 2) ? yz0.z : yz0.w;
                const float y1 = (b == 1) ? yz1.y : (b == 2) ? yz1.z : yz1.w;
                #pragma unroll
                for (int w = 1; w < 4; ++w) {
                    const int s = 1 + (w - 1) * 3 + (b - 1);
                    const float w0 = (w == 1) ? wv0.y : ((w == 2) ? wv0.z : wv0.w);
                    const float w1 = (w == 1) ? wv1.y : ((w == 2) ? wv1.z : wv1.w);
                    acc[s][0][0] = fmaf(w0, y0, acc[s][0][0]);
                    acc[s][0][1] = fmaf(w0, y1, acc[s][0][1]);
                    acc[s][1][0] = fmaf(w1, y0, acc[s][1][0]);
                    acc[s][1][1] = fmaf(w1, y1, acc[s][1][1]);
                }
            }
        }
    };

    // ================= pipelined phase loop ================================
    __syncthreads();             // A0: XT(0) + CT ready
    stage1(Y2[0]);               // S1(0) -> Y2[0]

    for (int p = 1; p < 8; ++p) {
        __syncthreads();         // B(p-1): Y2[p-1] complete; XT(p-1) readers done
        // ---- write XT(p) from prefetched regs; issue loads for p+1 ----
        *(float4*)(XT + xt0) = pre0;
        if (has1) *(float4*)(XT + xt1) = pre1;
        if (p < 7) {
            gsrc0 += 128000;
            pre0 = *(const float4*)gsrc0;     // lands during S2(p-1)+S1(p)
            if (has1) { gsrc1 += 128000; pre1 = *(const float4*)gsrc1; }
        }
        __syncthreads();         // A(p): XT(p) ready
        // ---- merged interval: S2 of previous phase + S1 of current ----
        stage2(Y2[(p - 1) & 1], W2 + (p - 1) * 1280 + c_e * 8);
        stage1(Y2[p & 1]);
    }
    __syncthreads();             // B(7): Y2[7] complete
    stage2(Y2[1], W2 + 7 * 1280 + c_e * 8);

    // ---- epilogue: SO(3)-grid + self-normalized pooling (2 e x 2 z) ----
    const float wi0 = w_i[0], wi1 = w_i[1], wi2 = w_i[2];
    float num[2][2], den[2][2];
    #pragma unroll
    for (int ee = 0; ee < 2; ++ee) { num[ee][0] = num[ee][1] = 0.f; den[ee][0] = den[ee][1] = 0.f; }
    #pragma unroll
    for (int q = 0; q < 27; ++q) {
        const float wl = ((q / 3) % 3 == 0) ? wi0 : (((q / 3) % 3 == 1) ? wi1 : wi2);
        float gv[10];
        #pragma unroll
        for (int s = 0; s < 10; ++s) gv[s] = g[q * 10 + s];  // uniform -> s_load
        #pragma unroll
        for (int ee = 0; ee < 2; ++ee) {
            #pragma unroll
            for (int zi = 0; zi < 2; ++zi) {
                float v = 0.f;
                #pragma unroll
                for (int s = 0; s < 10; ++s) v = fmaf(acc[s][ee][zi], gv[s], v);
                v = fmaxf(v, 0.f);
                den[ee][zi] = fmaf(v, wl, den[ee][zi]);
                num[ee][zi] = fmaf(v * v, wl, num[ee][zi]);
            }
        }
    }
    #pragma unroll
    for (int ee = 0; ee < 2; ++ee) {
        const int e = 2 * c_e + ee;
        const float bz = bias[e];
        float* op = out + (((bb * 16 + e) * 36 + xo) * 36 + (yoq * 4 + c_yo)) * 36
                        + zs * 12 + 2 * c_zt;
        *(float2*)op = make_float2(num[ee][0] / (den[ee][0] + 1e-16f) + bz,
                                   num[ee][1] / (den[ee][1] + 1e-16f) + bz);
    }
}

extern "C" void kernel_launch(void* const* d_in, const int* in_sizes, int n_in,
                              void* d_out, int out_size, void* d_ws, size_t ws_size,
                              hipStream_t stream) {
    const float* x          = (const float*)d_in[0];
    const float* weight     = (const float*)d_in[1];
    const float* zeroweight = (const float*)d_in[2];
    const float* bias       = (const float*)d_in[3];
    const float* g          = (const float*)d_in[4];
    const float* w_i        = (const float*)d_in[5];
    const float* bf         = (const float*)d_in[6];
    float* outp = (float*)d_out;

    float* W2  = (float*)d_ws;            // 10240 f32
    float* TAB = (float*)d_ws + 10240;    // 800 f32 (CT2 layout)

    prep_kernel<<<44, 256, 0, stream>>>(weight, zeroweight, bf, W2, TAB);
    // 1944 blocks = 36 xo * 9 yoq * 3 zs * 2 b, XCD-swizzled in-kernel
    fused_kernel<<<1944, 192, 0, stream>>>(x, W2, TAB, g, w_i, bias, outp);
}

// Round 5
// 153.108 us; speedup vs baseline: 17.2029x; 17.2029x over previous
//
#include <hip/hip_runtime.h>

// ---------------------------------------------------------------------------
// Factorized algorithm (verified rounds 2-11). Shells = ascending r2 rank:
//   r2 in {0,1,2,3,4,5,6,8,9,12} -> shell 0..9
// y[l][r][d][z] = sum_{taps t in shell r} sph_l[t] * x[d, xo+i, yo+j, z+kk]
// conv_r[s,e,z] = sum_{r,d} wfull[wig_w[s], r, e, d] * y[wig_b[s]][r][d][z]
// s=0:(w,b)=(0,0); s=1..9: w=1+(s-1)/3, b=1+(s-1)%3
// Round 17: LDS-throughput attack (r13-r15 showed the kernel is bound by
//   LDS instruction count, not stalls/conflicts). 4 super-phases of 4 d:
//   stage-1 decode (zt=wave3, sd4, l4, yo4), 4 z per thread:
//   - x-reads: 2 aligned ds_read_b128 per (i,j) (8 floats / 4 z) vs 6 b64
//   - CT packed by z-symmetry: sph_l(kk) = K_l*comp/sqrt(r2) gives
//     c4 = s*c0, c3 = s*c1 (s = -1 for l==2 else +1) -> one b128 [c0,c1,c2,s]
//     per (i,j); yreg += c0*(xv[z]+s*xv[z+4]) etc. (algebraically identical)
//   - Y2 40 k-rows with k-parity XOR on the 16-bank bit: stage-1 writes
//     2-way (free), stage-2 reads conflict-free. XT sd-pitch 808 -> <=2-way.
//   Stage-1/stage-2 stay in SEPARATE barrier intervals (r16 lesson: merging
//   unions live ranges -> scratch spill disaster). 8 barriers total.
//   LDS = Y2 30720 + XT 12928 + CT 1600 = 45248 B -> 3 blocks/CU.
//   NO __launch_bounds__ min-waves arg (r14: (192,4) => VGPR 64 => spills).
// ---------------------------------------------------------------------------

// prep: W2[p8][k20][e16][w4] (k=2r+di, d=2p+di) + CT3[l][25][4] packed
__global__ void prep_kernel(const float* __restrict__ weight,     // (4,9,16,16)
                            const float* __restrict__ zw,         // (16,16)
                            const float* __restrict__ bf,         // (4,10,125)
                            float* __restrict__ W2,               // 10240 f32
                            float* __restrict__ TAB)              // 400 f32
{
    int t = blockIdx.x * 256 + threadIdx.x;
    if (t < 10240) {
        int w = t & 3;
        int e = (t >> 2) & 15;
        int k = (t >> 6) % 20;
        int p = t / 1280;
        int r = k >> 1, di = k & 1, d = 2 * p + di;
        float v;
        if (r == 0) v = (w == 0) ? zw[e * 16 + d] : 0.f;
        else        v = weight[((w * 9 + (r - 1)) * 16 + e) * 16 + d];
        W2[t] = v;
    } else if (t < 10240 + 400) {
        int q = t - 10240;           // [l4][25][4] = {c(kk=0),c(1),c(2),sign}
        int l = q / 100;
        int rem = q % 100;
        int slice = rem / 4, qq = rem & 3;
        float s;
        if (qq == 3) {
            s = (l == 2) ? -1.f : 1.f;   // c(3)=s*c(1), c(4)=s*c(0)
        } else {
            s = 0.f;
            int tap = slice * 5 + qq;
            for (int r = 0; r < 10; ++r) s += bf[(l * 10 + r) * 125 + tap];
        }
        TAB[q] = s;                  // sph_l[tap] (masks partition the cube)
    }
}

__global__ __launch_bounds__(192) void fused_kernel(
    const float* __restrict__ x,    // (2,16,40,40,40)
    const float* __restrict__ W2,   // [p][k20][e16][w4]
    const float* __restrict__ TAB,  // CT3 [l][25][4]
    const float* __restrict__ g,    // (27,10)
    const float* __restrict__ w_i,  // (3,)
    const float* __restrict__ bias, // (16,)
    float* __restrict__ out)        // (2,16,36,36,36)
{
    __shared__ float Y2[7680];      // [k40][bank-permuted (yo,z,l)] see below
    __shared__ float CT[400];       // [l4][25][4] packed symmetric coeffs
    __shared__ float XT[3232];      // [sd4 pitch 808][i5][row8][20]

    const int tid = threadIdx.x;

    // XCD-chunked swizzle: 1944 blocks = 8 XCDs x 243 contiguous wgids
    const int bid  = blockIdx.x;
    const int wgid = (bid & 7) * 243 + (bid >> 3);
    const int xo  = wgid % 36;
    const int yoq = (wgid / 36) % 9;
    const int zs  = (wgid / 324) % 3;   // z base = 12*zs
    const int bb  = wgid / 972;

    // stage-1 decode: zt = wave (3), lane -> (sd4, l4, yo4); 4 z per thread
    const int s_zt = tid >> 6;          // 0..2, z = 4*s_zt + zz
    const int lane = tid & 63;
    const int s_sd = lane >> 4;         // 0..3  (d = 4*pp + s_sd)
    const int s_l  = (lane >> 2) & 3;
    const int s_yo = lane & 3;
    // stage-2 decode (e8, yo4, zt6): e = 2*c_e+{0,1}, z = 2*c_zt+{0,1}
    const int c_e  = tid & 7;
    const int c_yo = (tid >> 3) & 3;
    const int c_zt = tid / 32;

    for (int idx = tid; idx < 400; idx += 192) CT[idx] = TAB[idx];

    constexpr int RANKT[13] = {0, 1, 2, 3, 4, 5, 6, 0, 7, 8, 0, 0, 9};

    float acc[10][2][2];   // [s][e-sub][z] = 40 regs
    #pragma unroll
    for (int s = 0; s < 10; ++s)
        #pragma unroll
        for (int ee = 0; ee < 2; ++ee) { acc[s][ee][0] = 0.f; acc[s][ee][1] = 0.f; }

    // Y2 word(k', yo, z, l) = k'*192 + (z&1)*96 + (z>>2)*32
    //                         + (((z>>1)&1) ^ (k'&1))*16 + yo*4 + l
    // stage-1 writes: k'&1 == sd&1 -> bank = ((zz>>1)^(sd&1))*16+yo*4+l,
    //   distinct over (sd&1,yo,l)=32 banks, 2-way over sd>>1 (free).
    // stage-2 reads: per-instr uniform XOR -> 8 distinct 16B groups, clean.
    const int s1b  = s_sd & 1;
    const int kb   = (s_sd >> 1) * 20 + s1b;     // k' = kb + 2r
    const int wb0  = s_zt * 32 + s_yo * 4 + s_l;
    const int offa = s1b ? 16 : 0;               // zz=0,1 slot
    const int offb = 16 - offa;                  // zz=2,3 slot
    const int ybA  = (c_zt >> 1) * 32 + (c_zt & 1) * 16 + c_yo * 4;  // k' even
    const int ybB  = ybA ^ 16;                                        // k' odd

    // ---- XT staging geometry: 640 float4 per super-phase, 4 slots ----
    // decode j in LOW 3 bits -> conflict-free b128 LDS writes
    int xtoff[4], goff[4];
    #pragma unroll
    for (int q = 0; q < 4; ++q) {
        const int idx = tid + 192 * q;
        const int j  = idx & 7;
        const int zq = (idx >> 3) & 3;
        const int ii = (idx >> 5) % 5;
        const int sd = idx / 160;               // 0..3 (idx<640)
        xtoff[q] = sd * 808 + (ii * 8 + j) * 20 + 4 * zq;
        goff[q]  = sd * 64000 + ((xo + ii) * 40 + yoq * 4 + j) * 40
                   + zs * 12 + 4 * zq;
    }
    const bool has3 = tid < 64;                 // slot 3 active iff idx<640
    const float* xbase = x + bb * 1024000;

    // prologue: XT(0) direct; prefetch super-phase 1
    {
        float4 v0 = *(const float4*)(xbase + goff[0]);
        float4 v1 = *(const float4*)(xbase + goff[1]);
        float4 v2 = *(const float4*)(xbase + goff[2]);
        float4 v3 = has3 ? *(const float4*)(xbase + goff[3])
                         : make_float4(0.f, 0.f, 0.f, 0.f);
        *(float4*)(XT + xtoff[0]) = v0;
        *(float4*)(XT + xtoff[1]) = v1;
        *(float4*)(XT + xtoff[2]) = v2;
        if (has3) *(float4*)(XT + xtoff[3]) = v3;
    }
    float4 pre[4];
    {
        const float* b1 = xbase + 256000;
        pre[0] = *(const float4*)(b1 + goff[0]);
        pre[1] = *(const float4*)(b1 + goff[1]);
        pre[2] = *(const float4*)(b1 + goff[2]);
        pre[3] = has3 ? *(const float4*)(b1 + goff[3])
                      : make_float4(0.f, 0.f, 0.f, 0.f);
    }

    for (int pp = 0; pp < 4; ++pp) {
        __syncthreads();   // A: XT(pp) ready; stage-2(pp-1) done (Y2 free)
        // ---- stage 1: 4 z, d = 4*pp + s_sd, l = s_l (from XT) ----
        {
            float yreg[10][4];
            #pragma unroll
            for (int r = 0; r < 10; ++r) {
                yreg[r][0] = 0.f; yreg[r][1] = 0.f;
                yreg[r][2] = 0.f; yreg[r][3] = 0.f;
            }
            const float* xt  = XT + s_sd * 808 + 4 * s_zt;
            const float* ctp = CT + s_l * 100;
            #pragma unroll
            for (int i = 0; i < 5; ++i) {
                #pragma unroll
                for (int j = 0; j < 5; ++j) {
                    const float* rp = xt + (i * 8 + s_yo + j) * 20;
                    const float4 xa = *(const float4*)rp;
                    const float4 xb = *(const float4*)(rp + 4);
                    const float xv[8] = {xa.x, xa.y, xa.z, xa.w,
                                         xb.x, xb.y, xb.z, xb.w};
                    const float4 cc = *(const float4*)(ctp + (i * 5 + j) * 4);
                    const int dij = (i - 2) * (i - 2) + (j - 2) * (j - 2);
                    const int r04 = RANKT[dij + 4];
                    const int r13 = RANKT[dij + 1];
                    const int r2c = RANKT[dij];
                    #pragma unroll
                    for (int zz = 0; zz < 4; ++zz) {
                        const float t04 = fmaf(cc.w, xv[zz + 4], xv[zz]);
                        const float t13 = fmaf(cc.w, xv[zz + 3], xv[zz + 1]);
                        yreg[r04][zz] = fmaf(cc.x, t04, yreg[r04][zz]);
                        yreg[r13][zz] = fmaf(cc.y, t13, yreg[r13][zz]);
                        yreg[r2c][zz] = fmaf(cc.z, xv[zz + 2], yreg[r2c][zz]);
                    }
                }
            }
            #pragma unroll
            for (int r = 0; r < 10; ++r) {
                const int w0 = (kb + 2 * r) * 192 + wb0;
                Y2[w0 + offa]      = yreg[r][0];   // pairs fuse to ds_write2
                Y2[w0 + offa + 96] = yreg[r][1];
                Y2[w0 + offb]      = yreg[r][2];
                Y2[w0 + offb + 96] = yreg[r][3];
            }
        }
        __syncthreads();   // B: Y2 ready; XT(pp) readers done
        // ---- write XT(pp+1) from prefetch; issue loads for pp+2 ----
        if (pp < 3) {
            *(float4*)(XT + xtoff[0]) = pre[0];
            *(float4*)(XT + xtoff[1]) = pre[1];
            *(float4*)(XT + xtoff[2]) = pre[2];
            if (has3) *(float4*)(XT + xtoff[3]) = pre[3];
            if (pp < 2) {
                const float* bn = xbase + (pp + 2) * 256000;
                pre[0] = *(const float4*)(bn + goff[0]);
                pre[1] = *(const float4*)(bn + goff[1]);
                pre[2] = *(const float4*)(bn + goff[2]);
                if (has3) pre[3] = *(const float4*)(bn + goff[3]);
            }
        }
        // ---- stage 2 (E=2): acc[s][ee][z] += wfull * y over 40 k ----
        {
            const float* W2p = W2 + pp * 2560 + c_e * 8;
            #pragma unroll
            for (int k = 0; k < 40; ++k) {
                const float4 wv0 = *(const float4*)(W2p + k * 64);
                const float4 wv1 = *(const float4*)(W2p + k * 64 + 4);
                const float* yb = Y2 + k * 192 + ((k & 1) ? ybB : ybA);
                const float4 yz0 = *(const float4*)(yb);       // l0..3 at z0
                const float4 yz1 = *(const float4*)(yb + 96);  // l0..3 at z1
                {   // b = 0 pairs only with w = 0 -> s = 0
                    acc[0][0][0] = fmaf(wv0.x, yz0.x, acc[0][0][0]);
                    acc[0][0][1] = fmaf(wv0.x, yz1.x, acc[0][0][1]);
                    acc[0][1][0] = fmaf(wv1.x, yz0.x, acc[0][1][0]);
                    acc[0][1][1] = fmaf(wv1.x, yz1.x, acc[0][1][1]);
                }
                #pragma unroll
                for (int b = 1; b < 4; ++b) {
                    const float y0 = (b == 1) ? yz0.y : (b == 2) ? yz0.z : yz0.w;
                    const float y1 = (b == 1) ? yz1.y : (b == 2) ? yz1.z : yz1.w;
                    #pragma unroll
                    for (int w = 1; w < 4; ++w) {
                        const int s = 1 + (w - 1) * 3 + (b - 1);
                        const float w0 = (w == 1) ? wv0.y : ((w == 2) ? wv0.z : wv0.w);
                        const float w1 = (w == 1) ? wv1.y : ((w == 2) ? wv1.z : wv1.w);
                        acc[s][0][0] = fmaf(w0, y0, acc[s][0][0]);
                        acc[s][0][1] = fmaf(w0, y1, acc[s][0][1]);
                        acc[s][1][0] = fmaf(w1, y0, acc[s][1][0]);
                        acc[s][1][1] = fmaf(w1, y1, acc[s][1][1]);
                    }
                }
            }
        }
    }

    // ---- epilogue: SO(3)-grid + self-normalized pooling (2 e x 2 z) ----
    const float wi0 = w_i[0], wi1 = w_i[1], wi2 = w_i[2];
    float num[2][2], den[2][2];
    #pragma unroll
    for (int ee = 0; ee < 2; ++ee) { num[ee][0] = num[ee][1] = 0.f; den[ee][0] = den[ee][1] = 0.f; }
    #pragma unroll
    for (int q = 0; q < 27; ++q) {
        const float wl = ((q / 3) % 3 == 0) ? wi0 : (((q / 3) % 3 == 1) ? wi1 : wi2);
        float gv[10];
        #pragma unroll
        for (int s = 0; s < 10; ++s) gv[s] = g[q * 10 + s];  // uniform -> s_load
        #pragma unroll
        for (int ee = 0; ee < 2; ++ee) {
            #pragma unroll
            for (int zi = 0; zi < 2; ++zi) {
                float v = 0.f;
                #pragma unroll
                for (int s = 0; s < 10; ++s) v = fmaf(acc[s][ee][zi], gv[s], v);
                v = fmaxf(v, 0.f);
                den[ee][zi] = fmaf(v, wl, den[ee][zi]);
                num[ee][zi] = fmaf(v * v, wl, num[ee][zi]);
            }
        }
    }
    #pragma unroll
    for (int ee = 0; ee < 2; ++ee) {
        const int e = 2 * c_e + ee;
        const float bz = bias[e];
        float* op = out + (((bb * 16 + e) * 36 + xo) * 36 + (yoq * 4 + c_yo)) * 36
                        + zs * 12 + 2 * c_zt;
        *(float2*)op = make_float2(num[ee][0] / (den[ee][0] + 1e-16f) + bz,
                                   num[ee][1] / (den[ee][1] + 1e-16f) + bz);
    }
}

extern "C" void kernel_launch(void* const* d_in, const int* in_sizes, int n_in,
                              void* d_out, int out_size, void* d_ws, size_t ws_size,
                              hipStream_t stream) {
    const float* x          = (const float*)d_in[0];
    const float* weight     = (const float*)d_in[1];
    const float* zeroweight = (const float*)d_in[2];
    const float* bias       = (const float*)d_in[3];
    const float* g          = (const float*)d_in[4];
    const float* w_i        = (const float*)d_in[5];
    const float* bf         = (const float*)d_in[6];
    float* outp = (float*)d_out;

    float* W2  = (float*)d_ws;            // 10240 f32
    float* TAB = (float*)d_ws + 10240;    // 400 f32 (packed CT3 layout)

    prep_kernel<<<42, 256, 0, stream>>>(weight, zeroweight, bf, W2, TAB);
    // 1944 blocks = 36 xo * 9 yoq * 3 zs * 2 b, XCD-swizzled in-kernel
    fused_kernel<<<1944, 192, 0, stream>>>(x, W2, TAB, g, w_i, bias, outp);
}